// Round 2
// baseline (85.845 us; speedup 1.0000x reference)
//
#include <hip/hip_runtime.h>

#define NB 64
#define NPG 512
#define LIG 128
#define NBLK 1024          // 16 blocks per graph, 32 rows per block; exactly 4 blocks/CU
#define RPB 32             // rows per block
#define THREADS 512        // 8 waves

// sqrt-free radius tests, bit-exact vs the reference's norm<=cutoff:
// __fsqrt_rn(s) <= 10.0f  <=>  s <= 100 + 2^-17  (0x42C80001)
// __fsqrt_rn(s) <= 8.0f   <=>  s <= 64  + 2^-17  (0x42800001)
__device__ __forceinline__ float dist2(float dx, float dy, float dz) {
    return __fadd_rn(__fadd_rn(__fmul_rn(dx, dx), __fmul_rn(dy, dy)), __fmul_rn(dz, dz));
}
#define T10 __uint_as_float(0x42C80001u)
#define T8  __uint_as_float(0x42800001u)

#define F21 0x1FFFFFull

// unpack a published (flag|cc<<21|ci) word into the packed scan triple
// (cc<<42 | ci<<21 | red), where red = ci iff the source block is a ligand
// block (h = j < 4, valid because each lane scans blocks lane*16 + j).
__device__ __forceinline__ unsigned long long pk_triple(unsigned long long v, int j) {
    unsigned long long ci = v & F21;
    unsigned long long cc = (v >> 21) & F21;
    unsigned long long red = (j < 4) ? ci : 0ull;
    return (cc << 42) | (ci << 21) | red;
}

// Single fused kernel. Phase 1: masks + row counts into LDS, publish packed
// block partials via one device-scope atomic store. Phase 2: wave 0 spin-reads
// all 1024 partials (flag bit 63; grid is exactly co-resident at 4 blocks/CU,
// guaranteed by __launch_bounds__(512,8) -> VGPR<=64, LDS 8.7KB), packed
// 64-bit shuffle scan -> global bases, then emit from the LDS-resident masks.
// NOT a cooperative launch - graph-capture safe.
__global__ __launch_bounds__(THREADS, 8) void fused_kernel(const float* __restrict__ X,
                                                           unsigned long long* __restrict__ pk,
                                                           int* __restrict__ out) {
    __shared__ float s[NPG * 3];                   // 6 KB coords
    __shared__ unsigned long long smask[RPB * 8];  // 2 KB masks (persist to emit)
    __shared__ int rc[RPB], ri[RPB];               // per-row counts
    __shared__ int sc[RPB], si[RPB];               // global exclusive bases
    __shared__ unsigned long long sblkb, stot;
    __shared__ int sint;

    const int b = blockIdx.x;
    const int g = b >> 4;
    const int h = b & 15;                          // 16 row-groups of 32
    const int t = threadIdx.x;
    const int lane = t & 63;
    const int w = t >> 6;

    // ---------------- phase 1: count ----------------
    if (t < 384) ((float4*)s)[t] = ((const float4*)X)[g * 384 + t];
    if (t < RPB * 8) smask[t] = 0ull;
    __syncthreads();

    float cx[8], cy[8], cz[8];
#pragma unroll
    for (int k = 0; k < 8; ++k) {
        const int c = k * 64 + lane;
        cx[k] = s[3 * c]; cy[k] = s[3 * c + 1]; cz[k] = s[3 * c + 2];
    }

#pragma unroll
    for (int j = 0; j < 4; ++j) {
        const int lr = w * 4 + j;
        const int r = h * 32 + lr;
        const float px = s[3 * r], py = s[3 * r + 1], pz = s[3 * r + 2];
        int cc = 0, ci = 0;
        if (h < 4) {          // ligand rows
            if (r != 0) {
                unsigned long long mm[6];
#pragma unroll
                for (int k = 2; k < 8; ++k) {
                    unsigned long long m =
                        __ballot(dist2(px - cx[k], py - cy[k], pz - cz[k]) <= T10);
                    if (k == 2) m &= ~1ull;        // c=128 is global
                    mm[k - 2] = m;
                    ci += __popcll(m);
                }
                if (lane == 0) {                   // single exec toggle per row
#pragma unroll
                    for (int k = 0; k < 6; ++k) smask[lr * 8 + 2 + k] = mm[k];
                }
            }
        } else if (r != LIG) {  // protein rows
            unsigned long long mm[8];
#pragma unroll
            for (int k = 0; k < 2; ++k) {
                unsigned long long m =
                    __ballot(dist2(px - cx[k], py - cy[k], pz - cz[k]) <= T10);
                if (k == 0) m &= ~1ull;            // c=0 is global
                mm[k] = m;
                ci += __popcll(m);
            }
            const int kr = r >> 6;
            const unsigned long long selfbit = 1ull << (r & 63);
#pragma unroll
            for (int k = 2; k < 8; ++k) {
                unsigned long long m =
                    __ballot(dist2(px - cx[k], py - cy[k], pz - cz[k]) <= T8);
                if (k == 2) m &= ~1ull;            // c=128 is global
                if (k == kr) m &= ~selfbit;        // self edge
                mm[k] = m;
                cc += __popcll(m);
            }
            if (lane == 0) {
#pragma unroll
                for (int k = 0; k < 8; ++k) smask[lr * 8 + k] = mm[k];
            }
        }
        if (lane == 0) { rc[lr] = cc; ri[lr] = ci; }
    }
    __syncthreads();

    // ---------------- phase 2: publish + spin + scan (wave 0) ----------------
    if (w == 0) {
        // reduce the 32 row counts -> block partials
        int c = (lane < RPB) ? rc[lane] : 0;
        int ii = (lane < RPB) ? ri[lane] : 0;
#pragma unroll
        for (int off = 32; off >= 1; off >>= 1) {
            c += __shfl_down(c, off, 64);
            ii += __shfl_down(ii, off, 64);
        }
        if (lane == 0) {
            const unsigned long long q = (1ull << 63) |
                ((unsigned long long)(unsigned)c << 21) | (unsigned long long)(unsigned)ii;
            __hip_atomic_store(&pk[b], q, __ATOMIC_RELAXED, __HIP_MEMORY_SCOPE_AGENT);
        }
        // each lane spin-reads 16 blocks' partials; flag = bit 63.
        const int base = lane * 16;
        unsigned long long sum = 0;
#pragma unroll
        for (int j = 0; j < 16; ++j) {
            unsigned long long v =
                __hip_atomic_load(&pk[base + j], __ATOMIC_RELAXED, __HIP_MEMORY_SCOPE_AGENT);
            int guard = 0;
            while (!(v >> 63) && ++guard < (1 << 20)) {
                __builtin_amdgcn_s_sleep(8);
                v = __hip_atomic_load(&pk[base + j], __ATOMIC_RELAXED, __HIP_MEMORY_SCOPE_AGENT);
            }
            sum += pk_triple(v, j);
        }
        // packed 64-bit inclusive shuffle scan over 64 lanes
        unsigned long long incl = sum;
#pragma unroll
        for (int off = 1; off < 64; off <<= 1) {
            unsigned long long n = __shfl_up(incl, off, 64);
            if (lane >= off) incl += n;
        }
        if (lane == (b >> 4)) {                    // this lane owns block b's chunk
            unsigned long long e = incl - sum;     // exclusive prefix of the chunk
            const int idx = b & 15;
            for (int jj = 0; jj < idx; ++jj) {
                unsigned long long v =
                    __hip_atomic_load(&pk[base + jj], __ATOMIC_RELAXED, __HIP_MEMORY_SCOPE_AGENT);
                e += pk_triple(v, jj);             // flags already observed set above
            }
            sblkb = e;                             // block b's exclusive prefixes (packed)
        }
        if (lane == 63) stot = incl;               // grand totals (packed)
    }
    __syncthreads();

    const int blkb0 = (int)((sblkb >> 42) & F21);
    const int blkb1 = (int)((sblkb >> 21) & F21);
    const int blkb2 = (int)(sblkb & F21);
    const int Eci = (int)((stot >> 42) & F21);
    const int Ei  = (int)((stot >> 21) & F21);
    const int Er  = (int)(stot & F21);

    if (t < RPB) {  // row counts from LDS (phase 1) -> 32-lane shuffle scan
        const int mc = rc[t];
        const int mi = ri[t];
        int ic = mc, ii = mi;
#pragma unroll
        for (int off = 1; off < 32; off <<= 1) {
            int a0 = __shfl_up(ic, off, 64);
            int a1 = __shfl_up(ii, off, 64);
            if (lane >= off) { ic += a0; ii += a1; }
        }
        sc[t] = blkb0 + ic - mc;                   // global exclusive bases
        si[t] = blkb1 + ii - mi;
        if (t == RPB - 1) sint = ii;               // block's inter total
    }
    __syncthreads();

    const unsigned long long lmask = (1ull << lane) - 1ull;
    const int gn = g * NPG;
    const int Ectx = Eci + NB * 1020 + NB * 2;

    int* ctx_src   = out;
    int* ctx_dst   = out + Ectx;
    int* inter_src = out + 2 * Ectx;
    int* inter_dst = inter_src + Ei;
    int* red_bid   = out + 2 * Ectx + 2 * Ei;
    int* red_off   = red_bid + Er;

    for (int j = 0; j < 4; ++j) {
        const int lr = w * 4 + j;
        const int r = h * 32 + lr;
        const int row = gn + r;

        unsigned long long m[8];
#pragma unroll
        for (int k = 0; k < 8; ++k) m[k] = smask[lr * 8 + k];

        if (h < 4) {
            if (r == 0) {
                // global(seg0) -> ligand cols 1..127 at Eci + g*1020 + (c-1)
                for (int k = 0; k < 2; ++k) {
                    const int c = k * 64 + lane;
                    if (c >= 1 && c < LIG) {
                        const int pos = Eci + g * 1020 + (c - 1);
                        ctx_src[pos] = row; ctx_dst[pos] = gn + c;
                    }
                }
                if (lane == 0) {
                    const int pos = Eci + NB * 1020 + g * 2;  // (0,128)
                    ctx_src[pos] = row; ctx_dst[pos] = gn + LIG;
                }
            } else {  // ligand non-global: inter only (red arrays filled flat below)
                int ib = si[lr];
#pragma unroll
                for (int k = 2; k < 8; ++k) {
                    if (m[k]) {
                        if ((m[k] >> lane) & 1ull) {
                            const int c = k * 64 + lane;
                            const int p = __popcll(m[k] & lmask);
                            inter_src[ib + p] = row; inter_dst[ib + p] = gn + c;
                        }
                        ib += __popcll(m[k]);
                    }
                }
                if (lane == 0) {
                    const int pos = Eci + g * 1020 + (LIG - 1) + (r - 1);  // (r,0)
                    ctx_src[pos] = row; ctx_dst[pos] = gn;
                }
            }
        } else {
            if (r == LIG) {
                // global(seg1) -> protein cols 129..511 at Eci + g*1020 + 254 + (c-129)
                for (int k = 2; k < 8; ++k) {
                    const int c = k * 64 + lane;
                    if (c > LIG) {
                        const int pos = Eci + g * 1020 + 2 * (LIG - 1) + (c - LIG - 1);
                        ctx_src[pos] = row; ctx_dst[pos] = gn + c;
                    }
                }
                if (lane == 0) {
                    const int pos = Eci + NB * 1020 + g * 2 + 1;  // (128,0)
                    ctx_src[pos] = row; ctx_dst[pos] = gn;
                }
            } else {  // protein non-global
                int ib = si[lr];
#pragma unroll
                for (int k = 0; k < 2; ++k) {
                    if (m[k]) {
                        if ((m[k] >> lane) & 1ull) {
                            const int c = k * 64 + lane;
                            const int pos = ib + __popcll(m[k] & lmask);
                            inter_src[pos] = row; inter_dst[pos] = gn + c;
                        }
                        ib += __popcll(m[k]);
                    }
                }
                int cb = sc[lr];
#pragma unroll
                for (int k = 2; k < 8; ++k) {
                    if (m[k]) {
                        if ((m[k] >> lane) & 1ull) {
                            const int c = k * 64 + lane;
                            const int pos = cb + __popcll(m[k] & lmask);
                            ctx_src[pos] = row; ctx_dst[pos] = gn + c;
                        }
                        cb += __popcll(m[k]);
                    }
                }
                if (lane == 0) {
                    const int pos = Eci + g * 1020 + 2 * (LIG - 1) + (NPG - LIG - 1) + (r - LIG - 1);
                    ctx_src[pos] = row; ctx_dst[pos] = gn + LIG;  // (r,128)
                }
            }
        }
    }

    // flat constant fill of the reduced arrays for this block's ligand edges
    if (h < 4) {
        const int rb0 = blkb2;
        const int n = sint;
        for (int i = t; i < n; i += THREADS) {
            red_bid[rb0 + i] = g;
            red_off[rb0 + i] = gn;
        }
    }
}

extern "C" void kernel_launch(void* const* d_in, const int* in_sizes, int n_in,
                              void* d_out, int out_size, void* d_ws, size_t ws_size,
                              hipStream_t stream) {
    (void)in_sizes; (void)n_in; (void)out_size; (void)ws_size;
    const float* X = (const float*)d_in[0];
    unsigned long long* pk = (unsigned long long*)d_ws;  // [1024] packed partials+flag
    int* out = (int*)d_out;

    // clear flags each iteration (graph-capture-safe async fill, 8 KB)
    hipMemsetAsync(pk, 0, NBLK * sizeof(unsigned long long), stream);
    fused_kernel<<<NBLK, THREADS, 0, stream>>>(X, pk, out);
}